// Round 8
// baseline (215.838 us; speedup 1.0000x reference)
//
#include <hip/hip_runtime.h>

typedef __attribute__((ext_vector_type(4))) float f32x4;
typedef __attribute__((ext_vector_type(8))) short bf16x8;

#define LOG2E 1.44269504088896340736f
// lgkm-only barrier: LDS h-exchange must drain; global loads/stores stay in flight
#define BAR_LGKM() asm volatile("s_waitcnt lgkmcnt(0)\n\ts_barrier" ::: "memory")

__device__ __forceinline__ float bcf(unsigned u){ union{unsigned u;float f;}v; v.u=u; return v.f; }
__device__ __forceinline__ unsigned pkbf(float a, float b){
    unsigned w; asm("v_cvt_pk_bf16_f32 %0, %1, %2" : "=v"(w) : "v"(a), "v"(b)); return w;
}
__device__ __forceinline__ float ex2(float x){ return __builtin_amdgcn_exp2f(x); }
__device__ __forceinline__ float rcp_(float x){ return __builtin_amdgcn_rcpf(x); }

#define MFMA(a,b,c) __builtin_amdgcn_mfma_f32_16x16x32_bf16(a,b,c,0,0,0)

union FragU { unsigned w[4]; bf16x8 v; };

// split 8 f32 into hi/lo bf16 fragments
__device__ __forceinline__ void split8(const float* v, bf16x8 &fh, bf16x8 &fl){
    FragU H, L;
#pragma unroll
    for (int i=0;i<4;i++){
        unsigned w = pkbf(v[2*i], v[2*i+1]);
        H.w[i] = w;
        float ra = v[2*i]   - bcf(w<<16);
        float rb = v[2*i+1] - bcf(w & 0xffff0000u);
        L.w[i] = pkbf(ra, rb);
    }
    fh = H.v; fl = L.v;
}

// B-frag for packed x-MFMA: k = [xh(0-3), xl(4-7) | xh(8-11), 1@12, 1@13 | 0 | 0]
__device__ __forceinline__ void build_bx(const float4& x, int hi, FragU& B){
    unsigned w0 = pkbf(x.x, x.y), w1 = pkbf(x.z, x.w);
    float r0 = x.x - bcf(w0<<16), r1 = x.y - bcf(w0 & 0xffff0000u);
    float r2 = x.z - bcf(w1<<16), r3 = x.w - bcf(w1 & 0xffff0000u);
    unsigned l0 = pkbf(r0,r1), l1 = pkbf(r2,r3);
    const bool h01 = (hi < 2);
    B.w[0] = h01 ? w0 : 0u;
    B.w[1] = h01 ? w1 : 0u;
    B.w[2] = (hi==0) ? l0 : (hi==1 ? 0x3f803f80u : 0u);
    B.w[3] = (hi==0) ? l1 : 0u;
}

// i16x8 -> exact hi/lo bf16 fragments
__device__ __forceinline__ void dec_q(const uint4& xw, FragU& Xh, FragU& Xl){
    float xv[8];
    xv[0]=(float)(short)(xw.x & 0xffffu); xv[1]=(float)((int)xw.x >> 16);
    xv[2]=(float)(short)(xw.y & 0xffffu); xv[3]=(float)((int)xw.y >> 16);
    xv[4]=(float)(short)(xw.z & 0xffffu); xv[5]=(float)((int)xw.z >> 16);
    xv[6]=(float)(short)(xw.w & 0xffffu); xv[7]=(float)((int)xw.w >> 16);
    split8(xv, Xh.v, Xl.v);
}

// write this lane's 4 h-values (j = 16wv+4hi+p) as bf16 hi/lo into hbuf
__device__ __forceinline__ void write_h_pair(unsigned (*hb)[16][20], int b15, int hi, int wv_,
                                             const float* hvv){
    unsigned h0 = pkbf(hvv[0], hvv[1]);
    unsigned h1 = pkbf(hvv[2], hvv[3]);
    float r0 = hvv[0]-bcf(h0<<16), r1 = hvv[1]-bcf(h0 & 0xffff0000u);
    float r2 = hvv[2]-bcf(h1<<16), r3 = hvv[3]-bcf(h1 & 0xffff0000u);
    unsigned l0 = pkbf(r0,r1), l1 = pkbf(r2,r3);
    const int wi = 8*wv_ + 2*hi;
    *(uint2*)&hb[0][b15][wi] = make_uint2(h0,h1);
    *(uint2*)&hb[1][b15][wi] = make_uint2(l0,l1);
}

// R3 shape (2 waves x 4 chains), out1 in global ws, lgkm-only in-loop barriers
__global__ __launch_bounds__(128) void lstm2_g(
    const float* __restrict__ xin,   // [8192,64,4]
    const float* __restrict__ sfc,   // [8192,5]
    const float* __restrict__ w_sfc1, const float* __restrict__ b_sfc1,
    const float* __restrict__ w_sfc2, const float* __restrict__ b_sfc2,
    const float* __restrict__ w_ih1, const float* __restrict__ w_hh1,
    const float* __restrict__ b_ih1, const float* __restrict__ b_hh1,
    const float* __restrict__ w_ih2, const float* __restrict__ w_hh2,
    const float* __restrict__ b_ih2, const float* __restrict__ b_hh2,
    const float* __restrict__ w_out, const float* __restrict__ b_out,
    float* __restrict__ outp,        // [8192,64,1]
    unsigned* __restrict__ ws)       // out1 history: 16384 uints per block
{
    __shared__ __align__(16) unsigned hbuf[2][2][16][20];   // [par][hi/lo][b][20w]
    __shared__ float ybuf[2][64][16];

    const int tid  = threadIdx.x;
    const int wv   = tid >> 6;
    const int lane = tid & 63;
    const int b15  = lane & 15;
    const int hi   = (lane >> 4) & 3;
    const int B0   = blockIdx.x * 16;
    unsigned* wsb  = ws + blockIdx.x * 16384;

    // ---------------- weights (R3 layout, unchanged) ---------------------------
    bf16x8 Whh_h[4], Whh_l[4], WxA[4];
    bf16x8 W2h_h[4], W2h_l[4], W2x_h[4], W2x_l[4];
    float bia[4][4], woutr[4];
#pragma unroll
    for (int c=0;c<4;c++){
        const int gr = 32*c + 16*wv + b15;
        const float sc = (c==2) ? (2.0f*LOG2E) : (-LOG2E);
        float wvv[8];
        {
            float4 wa = *(const float4*)(w_hh1 + gr*32 + 8*hi);
            float4 wb = *(const float4*)(w_hh1 + gr*32 + 8*hi + 4);
            wvv[0]=wa.x*sc; wvv[1]=wa.y*sc; wvv[2]=wa.z*sc; wvv[3]=wa.w*sc;
            wvv[4]=wb.x*sc; wvv[5]=wb.y*sc; wvv[6]=wb.z*sc; wvv[7]=wb.w*sc;
        }
        split8(wvv, Whh_h[c], Whh_l[c]);
        {
            float4 wi = *(const float4*)(w_ih1 + gr*4);
            float wh0=wi.x*sc, wh1=wi.y*sc, wh2=wi.z*sc, wh3=wi.w*sc;
            unsigned xw0 = pkbf(wh0,wh1), xw1 = pkbf(wh2,wh3);
            float wl0 = wh0-bcf(xw0<<16), wl1 = wh1-bcf(xw0 & 0xffff0000u);
            float wl2 = wh2-bcf(xw1<<16), wl3 = wh3-bcf(xw1 & 0xffff0000u);
            unsigned lw0 = pkbf(wl0,wl1), lw1 = pkbf(wl2,wl3);
            float bias = (b_ih1[gr] + b_hh1[gr])*sc;
            unsigned bh = pkbf(bias, 0.0f);
            float blo = bias - bcf(bh<<16);
            unsigned bword = pkbf(bias, blo);
            FragU A;
            if (hi==0){ A.w[0]=xw0; A.w[1]=xw1; A.w[2]=xw0; A.w[3]=xw1; }
            else if (hi==1){ A.w[0]=lw0; A.w[1]=lw1; A.w[2]=bword; A.w[3]=0u; }
            else { A.w[0]=0u; A.w[1]=0u; A.w[2]=0u; A.w[3]=0u; }
            WxA[c] = A.v;
        }
        {
            float4 wa = *(const float4*)(w_hh2 + gr*32 + 8*hi);
            float4 wb = *(const float4*)(w_hh2 + gr*32 + 8*hi + 4);
            wvv[0]=wa.x*sc; wvv[1]=wa.y*sc; wvv[2]=wa.z*sc; wvv[3]=wa.w*sc;
            wvv[4]=wb.x*sc; wvv[5]=wb.y*sc; wvv[6]=wb.z*sc; wvv[7]=wb.w*sc;
        }
        split8(wvv, W2h_h[c], W2h_l[c]);
        {
            const float scx = sc * (1.0f/32767.0f);
            float4 wa = *(const float4*)(w_ih2 + gr*32 + 8*hi);
            float4 wb = *(const float4*)(w_ih2 + gr*32 + 8*hi + 4);
            wvv[0]=wa.x*scx; wvv[1]=wa.y*scx; wvv[2]=wa.z*scx; wvv[3]=wa.w*scx;
            wvv[4]=wb.x*scx; wvv[5]=wb.y*scx; wvv[6]=wb.z*scx; wvv[7]=wb.w*scx;
        }
        split8(wvv, W2x_h[c], W2x_l[c]);
    }
#pragma unroll
    for (int p=0;p<4;p++){
        const int j = 16*wv + 4*hi + p;
        bia[0][p] = (b_ih2[j]    + b_hh2[j])    * (-LOG2E);
        bia[1][p] = (b_ih2[32+j] + b_hh2[32+j]) * (-LOG2E);
        bia[2][p] = (b_ih2[64+j] + b_hh2[64+j]) * (2.0f*LOG2E);
        bia[3][p] = (b_ih2[96+j] + b_hh2[96+j]) * (-LOG2E);
        woutr[p]  = w_out[j];
    }

    // ---------------- surface MLP -> h0, cs0 -----------------------------------
    float cs[4], hvv[4];
    {
        const float* sp = sfc + (B0 + b15)*5;
        const float s0=sp[0], s1=sp[1], s2=sp[2], s3=sp[3], s4=sp[4];
#pragma unroll
        for (int p=0;p<4;p++){
            const int j = 16*wv + 4*hi + p;
            float a1 = b_sfc1[j] + s0*w_sfc1[j*5+0] + s1*w_sfc1[j*5+1]
                     + s2*w_sfc1[j*5+2] + s3*w_sfc1[j*5+3] + s4*w_sfc1[j*5+4];
            float a2 = b_sfc2[j] + s0*w_sfc2[j*5+0] + s1*w_sfc2[j*5+1]
                     + s2*w_sfc2[j*5+2] + s3*w_sfc2[j*5+3] + s4*w_sfc2[j*5+4];
            hvv[p] = 1.0f - 2.0f*rcp_(ex2((2.0f*LOG2E)*a1)+1.0f);
            cs[p] = (2.0f*LOG2E)*(1.0f - 2.0f*rcp_(ex2((2.0f*LOG2E)*a2)+1.0f));
        }
    }
    write_h_pair(hbuf[0], b15, hi, wv, hvv);
    __syncthreads();

    // ---------------- phase 1: layer-1 LSTM, reversed time ---------------------
    // pipeline: Bx = frag(x[t]); xraw = x[t-1] loaded; load x[t-2] at iter top
    int par = 0;
    FragU Bx;
    float4 xraw;
    {
        float4 x0 = *(const float4*)(xin + ((B0 + b15)*64 + 63)*4);
        build_bx(x0, hi, Bx);
        xraw = *(const float4*)(xin + ((B0 + b15)*64 + 62)*4);
    }
#pragma unroll 1
    for (int t=63; t>=0; --t){
        float4 xnext;
        if (t >= 2) xnext = *(const float4*)(xin + ((B0 + b15)*64 + (t-2))*4);
        bf16x8 Hh = *(const bf16x8*)&hbuf[par][0][b15][4*hi];
        bf16x8 Hl = *(const bf16x8*)&hbuf[par][1][b15][4*hi];
        f32x4 acc[4];
#pragma unroll
        for (int c=0;c<4;c++){
            f32x4 a = {0.f,0.f,0.f,0.f};
            a = MFMA(WxA[c],   Bx.v, a);
            a = MFMA(Whh_h[c], Hh,   a);
            a = MFMA(Whh_h[c], Hl,   a);
            a = MFMA(Whh_l[c], Hh,   a);
            acc[c] = a;
        }
        int q[4];
#pragma unroll
        for (int p=0;p<4;p++){
            float iv = acc[0][p], fv = acc[1][p], gv = acc[2][p], ov = acc[3][p];
            float si = rcp_(1.0f+ex2(iv));
            float sf = rcp_(1.0f+ex2(fv));
            float so = rcp_(1.0f+ex2(ov));
            float tg = 1.0f - 2.0f*rcp_(ex2(gv)+1.0f);
            cs[p] = fmaf(sf, cs[p], ((2.0f*LOG2E)*si)*tg);
            float tc = 1.0f - 2.0f*rcp_(ex2(cs[p])+1.0f);
            hvv[p] = so*tc;
            q[p] = __float2int_rn(hvv[p]*32767.0f);
        }
        // out1 -> GLOBAL (fire-and-forget; lgkm barrier never drains it)
        unsigned q01 = ((unsigned)q[0] & 0xffffu) | ((unsigned)q[1] << 16);
        unsigned q23 = ((unsigned)q[2] & 0xffffu) | ((unsigned)q[3] << 16);
        *(uint2*)&wsb[(t*16 + b15)*16 + 8*wv + 2*hi] = make_uint2(q01, q23);
        write_h_pair(hbuf[par^1], b15, hi, wv, hvv);
        if (t) build_bx(xraw, hi, Bx);     // consume last iter's load (latency covered)
        xraw = xnext;
        BAR_LGKM();
        par ^= 1;
    }

    // ---------------- phase 1 -> 2 transition ----------------------------------
    {
        const int wi = 8*wv + 2*hi;
        *(uint2*)&hbuf[par][0][b15][wi] = make_uint2(0u,0u);
        *(uint2*)&hbuf[par][1][b15][wi] = make_uint2(0u,0u);
        cs[0]=0.f; cs[1]=0.f; cs[2]=0.f; cs[3]=0.f;
    }
    __syncthreads();   // full drain: out1 stores visible to all waves before reads
    FragU Xh, Xl;
    uint4 xwraw;
    {
        const uint4 xw0 = *(const uint4*)&wsb[(0*16 + b15)*16 + 4*hi];
        dec_q(xw0, Xh, Xl);
        xwraw = *(const uint4*)&wsb[(1*16 + b15)*16 + 4*hi];
    }

    // ---------------- phase 2: layer-2 LSTM + fused output ---------------------
#pragma unroll 1
    for (int t=0; t<64; ++t){
        const int tn2 = (t < 62) ? t+2 : 63;
        const uint4 xwnext = *(const uint4*)&wsb[(tn2*16 + b15)*16 + 4*hi];
        bf16x8 Hh = *(const bf16x8*)&hbuf[par][0][b15][4*hi];
        bf16x8 Hl = *(const bf16x8*)&hbuf[par][1][b15][4*hi];
        f32x4 acc[4];
#pragma unroll
        for (int c=0;c<4;c++){
            f32x4 a = {0.f,0.f,0.f,0.f};
            a = MFMA(W2x_h[c], Xh.v, a);
            a = MFMA(W2x_h[c], Xl.v, a);
            a = MFMA(W2x_l[c], Xh.v, a);
            a = MFMA(W2h_h[c], Hh,   a);
            a = MFMA(W2h_h[c], Hl,   a);
            a = MFMA(W2h_l[c], Hh,   a);
            acc[c] = a;
        }
        float y = 0.0f;
#pragma unroll
        for (int p=0;p<4;p++){
            float iv = acc[0][p] + bia[0][p];
            float fv = acc[1][p] + bia[1][p];
            float gv = acc[2][p] + bia[2][p];
            float ov = acc[3][p] + bia[3][p];
            float si = rcp_(1.0f+ex2(iv));
            float sf = rcp_(1.0f+ex2(fv));
            float so = rcp_(1.0f+ex2(ov));
            float tg = 1.0f - 2.0f*rcp_(ex2(gv)+1.0f);
            cs[p] = fmaf(sf, cs[p], ((2.0f*LOG2E)*si)*tg);
            float tc = 1.0f - 2.0f*rcp_(ex2(cs[p])+1.0f);
            hvv[p] = so*tc;
            y = fmaf(hvv[p], woutr[p], y);
        }
        y += __shfl_xor(y, 16, 64);
        y += __shfl_xor(y, 32, 64);
        if (hi == 0) ybuf[wv][t][b15] = y;
        write_h_pair(hbuf[par^1], b15, hi, wv, hvv);
        dec_q(xwraw, Xh, Xl);              // consume last iter's load
        xwraw = xwnext;
        BAR_LGKM();
        par ^= 1;
    }

    // ---------------- epilogue: combine wave halves, coalesced store -----------
    const float bo = b_out[0];
    const int bb = tid >> 3;
    const int t0 = (tid & 7) * 8;
#pragma unroll
    for (int hlf=0; hlf<2; ++hlf){
        float4 v;
        v.x = ybuf[0][t0+4*hlf+0][bb] + ybuf[1][t0+4*hlf+0][bb] + bo;
        v.y = ybuf[0][t0+4*hlf+1][bb] + ybuf[1][t0+4*hlf+1][bb] + bo;
        v.z = ybuf[0][t0+4*hlf+2][bb] + ybuf[1][t0+4*hlf+2][bb] + bo;
        v.w = ybuf[0][t0+4*hlf+3][bb] + ybuf[1][t0+4*hlf+3][bb] + bo;
        *(float4*)(outp + (B0 + bb)*64 + t0 + 4*hlf) = v;
    }
}

extern "C" void kernel_launch(void* const* d_in, const int* in_sizes, int n_in,
                              void* d_out, int out_size, void* d_ws, size_t ws_size,
                              hipStream_t stream) {
    const float* xin    = (const float*)d_in[0];
    const float* sfc    = (const float*)d_in[1];
    const float* w_sfc1 = (const float*)d_in[2];
    const float* b_sfc1 = (const float*)d_in[3];
    const float* w_sfc2 = (const float*)d_in[4];
    const float* b_sfc2 = (const float*)d_in[5];
    const float* w_ih1  = (const float*)d_in[6];
    const float* w_hh1  = (const float*)d_in[7];
    const float* b_ih1  = (const float*)d_in[8];
    const float* b_hh1  = (const float*)d_in[9];
    const float* w_ih2  = (const float*)d_in[10];
    const float* w_hh2  = (const float*)d_in[11];
    const float* b_ih2  = (const float*)d_in[12];
    const float* b_hh2  = (const float*)d_in[13];
    const float* w_out  = (const float*)d_in[14];
    const float* b_out  = (const float*)d_in[15];
    float* out = (float*)d_out;

    hipLaunchKernelGGL(lstm2_g, dim3(512), dim3(128), 0, stream,
                       xin, sfc, w_sfc1, b_sfc1, w_sfc2, b_sfc2,
                       w_ih1, w_hh1, b_ih1, b_hh1,
                       w_ih2, w_hh2, b_ih2, b_hh2,
                       w_out, b_out, out, (unsigned*)d_ws);
}